// Round 6
// baseline (237.954 us; speedup 1.0000x reference)
//
#include <hip/hip_runtime.h>
#include <hip/hip_bf16.h>

#define B_ 128
#define L_ 1024
#define T_ 64
#define CSH 5
#define C_ 32

using short8 = __attribute__((ext_vector_type(8))) short;
using f32x4  = __attribute__((ext_vector_type(4))) float;
using f32x16 = __attribute__((ext_vector_type(16))) float;

static __device__ __forceinline__ unsigned short bfb(float x) {
  return __builtin_bit_cast(unsigned short, __float2bfloat16(x));
}
static __device__ __forceinline__ float asf(unsigned u) { return __builtin_bit_cast(float, u); }
static __device__ __forceinline__ float bf2f(unsigned short b) { return asf(((unsigned)b) << 16); }
static __device__ __forceinline__ unsigned pk2(float lo, float hi) {
  __hip_bfloat162 h = __float22bfloat162_rn(float2{lo, hi});
  unsigned u;
  __builtin_memcpy(&u, &h, 4);
  return u;
}
// packed 2xf32 -> bf16x2 dword by TRUNCATION: one v_perm_b32 (verified r8)
static __device__ __forceinline__ unsigned pk2t(float lo, float hi) {
  return __builtin_amdgcn_perm(__builtin_bit_cast(unsigned, hi),
                               __builtin_bit_cast(unsigned, lo), 0x07060302u);
}
// gfx950 half-wave exchange (verified r5)
static __device__ __forceinline__ void pswap(unsigned& x, unsigned& y) {
  asm("v_permlane32_swap_b32 %0, %1" : "+v"(x), "+v"(y));
}

// ---------- K0: build Wswz table + zero score/out (r2-verified, 16 blocks) ----------
__global__ __launch_bounds__(256) void k_prep(const float* __restrict__ W,
                                              unsigned short* __restrict__ Wswz,
                                              float* __restrict__ score,
                                              float* __restrict__ out) {
  if (blockIdx.x == 0) {
    if (threadIdx.x < 128) score[threadIdx.x] = 0.f;
    if (threadIdx.x == 0) out[0] = 0.f;
  }
  const int t = blockIdx.x * 256 + threadIdx.x;
  const int e = t * 4, k = e >> 6, n0 = e & 63;
  float4 w4 = *(const float4*)(W + e);
  const int base = ((k >> 5) << 11) + ((n0 >> 4) << 9) + (((k >> 3) & 3) << 7) +
                   ((n0 & 15) << 3) + (k & 7);
  Wswz[base + 0]  = bfb(w4.x);
  Wswz[base + 8]  = bfb(w4.y);
  Wswz[base + 16] = bfb(w4.z);
  Wswz[base + 24] = bfb(w4.w);
}

// ---------- K1: emission + scan + gold. NEW (this round): ILP-2 — each wave owns
// TWO adjacent jobs (same batch row b, chunks c and c+1): two fully independent
// scan recursions interleaved in-register. Doubles independent MFMA/VALU chains
// per wave (latency hiding) with zero added synchronization. B-operand short8
// build hoisted out of the I-loop (VALU diet). Grid 512x256. ----------
__global__ __launch_bounds__(256) void k_scan(const int* __restrict__ x,
                                              const int* __restrict__ tags,
                                              const float* __restrict__ embed,
                                              const unsigned short* __restrict__ Wswz,
                                              const float* __restrict__ bias,
                                              const float* __restrict__ trans,
                                              uint4* __restrict__ XT,
                                              float* __restrict__ rlog,
                                              float* __restrict__ score) {
  __shared__ __align__(16) unsigned short Ftile[4][2][2048];  // 32 KB
  const int wv = threadIdx.x >> 6, L = threadIdx.x & 63;
  const int job0 = blockIdx.x * 8 + wv * 2;  // even c in 0..30
  const int job1 = job0 + 1;
  const int c0 = job0 & (C_ - 1);
  const int b = job0 >> CSH;
  const int a0 = 1 + c0 * 32, a1 = a0 + 32;
  const int len1 = min(32, 1024 - a1);  // 31 only for c1==31
  const int nh = L & 31, hh = L >> 5;
  const int m = L & 15, q = L >> 4;
  unsigned short* Ft0 = Ftile[wv][0];
  unsigned short* Ft1 = Ftile[wv][1];
  const int* tg = tags + (size_t)b * L_;

  const float bj0 = bias[m], bj1 = bias[16 + m], bj2 = bias[32 + m], bj3 = bias[48 + m];
#pragma unroll
  for (int jb = 0; jb < 2; jb++) {
    unsigned short* Ftj = jb ? Ft1 : Ft0;
    const int aj = jb ? a1 : a0;
    for (int p = 0; p < 2; p++) {
      int tok = aj + 16 * p + m;
      if (tok > 1023) tok = 1023;
      const float* er = embed + (size_t)x[b * 1024 + tok] * 256;
      f32x4 acc[4] = {{0.f,0.f,0.f,0.f},{0.f,0.f,0.f,0.f},{0.f,0.f,0.f,0.f},{0.f,0.f,0.f,0.f}};
#pragma unroll
      for (int kap = 0; kap < 8; kap++) {
        float4 p0 = *(const float4*)(er + 32 * kap + 8 * q);
        float4 p1 = *(const float4*)(er + 32 * kap + 8 * q + 4);
        unsigned u0 = pk2(p0.x, p0.y), u1 = pk2(p0.z, p0.w);
        unsigned u2 = pk2(p1.x, p1.y), u3 = pk2(p1.z, p1.w);
        short8 af = __builtin_bit_cast(short8, make_uint4(u0, u1, u2, u3));
#pragma unroll
        for (int u = 0; u < 4; u++) {
          short8 bf8 = *(const short8*)&Wswz[kap * 2048 + u * 512 + q * 128 + m * 8];
          acc[u] = __builtin_amdgcn_mfma_f32_16x16x32_bf16(af, bf8, acc[u], 0, 0, 0);
        }
      }
#pragma unroll
      for (int r = 0; r < 4; r++) {
        float e0 = acc[0][r] + bj0, e1 = acc[1][r] + bj1;
        float e2 = acc[2][r] + bj2, e3 = acc[3][r] + bj3;
        float mr = fmaxf(fmaxf(e0, e1), fmaxf(e2, e3));
#pragma unroll
        for (int off = 1; off < 16; off <<= 1) mr = fmaxf(mr, __shfl_xor(mr, off));
        float x0 = __expf(e0 - mr), x1 = __expf(e1 - mr);
        float x2 = __expf(e2 - mr), x3 = __expf(e3 - mr);
        float sr = (x0 + x1) + (x2 + x3);
#pragma unroll
        for (int off = 1; off < 16; off <<= 1) sr += __shfl_xor(sr, off);
        float rs = 1.0f / sr;
        const int row = 16 * p + 4 * q + r;
        Ftj[row * 64 + m]      = bfb(x0 * rs);
        Ftj[row * 64 + 16 + m] = bfb(x1 * rs);
        Ftj[row * 64 + 32 + m] = bfb(x2 * rs);
        Ftj[row * 64 + 48 + m] = bfb(x3 * rs);
      }
    }
  }
  // distributed gold partials (r14-verified), both jobs (same b -> one atomic)
  {
    float gold = 0.f;
    if (L < 32) {
      const int tga = tg[a0 + L], tgp = tg[a0 - 1 + L];
      gold += __logf(bf2f(Ft0[L * 64 + tga])) + trans[tgp * T_ + tga];
    }
    if (L < len1) {
      const int tga = tg[a1 + L], tgp = tg[a1 - 1 + L];
      gold += __logf(bf2f(Ft1[L * 64 + tga])) + trans[tgp * T_ + tga];
    }
#pragma unroll
    for (int off = 1; off < 64; off <<= 1) gold += __shfl_xor(gold, off);
    if (L == 0) atomicAdd(&score[b], gold);
  }

  short8 Af[2][4];
#pragma unroll
  for (int I = 0; I < 2; I++)
#pragma unroll
    for (int kap = 0; kap < 4; kap++) {
      short8 aa;
#pragma unroll
      for (int d = 0; d < 8; d++) {
        const int k = 16 * kap + 8 * hh + d;
        aa[d] = (short)bfb(__expf(trans[k * T_ + 32 * I + nh]));
      }
      Af[I][kap] = aa;
    }
  unsigned Bf0[4][2][4], Bf1[4][2][4];
#pragma unroll
  for (int kap = 0; kap < 4; kap++)
#pragma unroll
    for (int J = 0; J < 2; J++)
#pragma unroll
      for (int dw = 0; dw < 4; dw++) {
        int k0 = 16 * kap + 8 * hh + 2 * dw, n = 32 * J + nh;
        unsigned u = 0;
        if (k0 == n) u = 0x3F80u;
        if (k0 + 1 == n) u = 0x3F800000u;
        Bf0[kap][J][dw] = u;
        Bf1[kap][J][dw] = u;
      }

  float logacc0 = 0.f, logacc1 = 0.f;
  const f32x16 Z = {};
  for (int s = 0; s < 32; s++) {  // r13-verified body, two interleaved jobs
    const bool do1 = (s < len1);  // wave-uniform; false only at s=31 for c1==31
    const bool rn = ((s & 15) == 15);
    uint2 Fc0[2][4], Fc1[2][4];
#pragma unroll
    for (int I = 0; I < 2; I++)
#pragma unroll
      for (int j = 0; j < 4; j++)
        Fc0[I][j] = *(const uint2*)&Ft0[s * 64 + (16 * I + 4 * j + 2 * hh) * 2];
    if (do1) {
#pragma unroll
      for (int I = 0; I < 2; I++)
#pragma unroll
        for (int j = 0; j < 4; j++)
          Fc1[I][j] = *(const uint2*)&Ft1[s * 64 + (16 * I + 4 * j + 2 * hh) * 2];
    }
    float rs0 = 1.0f, rs1 = 1.0f;
#pragma unroll
    for (int J = 0; J < 2; J++) {
      short8 bk0[4], bk1[4];
#pragma unroll
      for (int kap = 0; kap < 4; kap++)
        bk0[kap] = __builtin_bit_cast(short8,
            make_uint4(Bf0[kap][J][0], Bf0[kap][J][1], Bf0[kap][J][2], Bf0[kap][J][3]));
      if (do1) {
#pragma unroll
        for (int kap = 0; kap < 4; kap++)
          bk1[kap] = __builtin_bit_cast(short8,
              make_uint4(Bf1[kap][J][0], Bf1[kap][J][1], Bf1[kap][J][2], Bf1[kap][J][3]));
      }
      f32x16 D0[2], D1[2];
#pragma unroll
      for (int I = 0; I < 2; I++) {
        f32x16 d = __builtin_amdgcn_mfma_f32_32x32x16_bf16(Af[I][0], bk0[0], Z, 0, 0, 0);
#pragma unroll
        for (int kap = 1; kap < 4; kap++)
          d = __builtin_amdgcn_mfma_f32_32x32x16_bf16(Af[I][kap], bk0[kap], d, 0, 0, 0);
        D0[I] = d;
      }
      if (do1) {
#pragma unroll
        for (int I = 0; I < 2; I++) {
          f32x16 d = __builtin_amdgcn_mfma_f32_32x32x16_bf16(Af[I][0], bk1[0], Z, 0, 0, 0);
#pragma unroll
          for (int kap = 1; kap < 4; kap++)
            d = __builtin_amdgcn_mfma_f32_32x32x16_bf16(Af[I][kap], bk1[kap], d, 0, 0, 0);
          D1[I] = d;
        }
      }
#pragma unroll
      for (int I = 0; I < 2; I++)
#pragma unroll
        for (int j = 0; j < 4; j++) {
          uint2 g = Fc0[I][j];
          D0[I][4 * j + 0] *= asf(g.x << 16);
          D0[I][4 * j + 1] *= asf(g.x & 0xffff0000u);
          D0[I][4 * j + 2] *= asf(g.y << 16);
          D0[I][4 * j + 3] *= asf(g.y & 0xffff0000u);
        }
      if (do1) {
#pragma unroll
        for (int I = 0; I < 2; I++)
#pragma unroll
          for (int j = 0; j < 4; j++) {
            uint2 g = Fc1[I][j];
            D1[I][4 * j + 0] *= asf(g.x << 16);
            D1[I][4 * j + 1] *= asf(g.x & 0xffff0000u);
            D1[I][4 * j + 2] *= asf(g.y << 16);
            D1[I][4 * j + 3] *= asf(g.y & 0xffff0000u);
          }
      }
      if (rn) {
        if (J == 0) {
          float mx0 = D0[0][0];
#pragma unroll
          for (int I = 0; I < 2; I++)
#pragma unroll
            for (int r = 0; r < 16; r++) mx0 = fmaxf(mx0, D0[I][r]);
#pragma unroll
          for (int off = 1; off < 64; off <<= 1) mx0 = fmaxf(mx0, __shfl_xor(mx0, off));
          rs0 = 1.0f / mx0;
          logacc0 += __logf(mx0);
          if (do1) {
            float mx1 = D1[0][0];
#pragma unroll
            for (int I = 0; I < 2; I++)
#pragma unroll
              for (int r = 0; r < 16; r++) mx1 = fmaxf(mx1, D1[I][r]);
#pragma unroll
            for (int off = 1; off < 64; off <<= 1) mx1 = fmaxf(mx1, __shfl_xor(mx1, off));
            rs1 = 1.0f / mx1;
            logacc1 += __logf(mx1);
          }
        }
#pragma unroll
        for (int I = 0; I < 2; I++)
#pragma unroll
          for (int r = 0; r < 16; r++) D0[I][r] *= rs0;
        if (do1) {
#pragma unroll
          for (int I = 0; I < 2; I++)
#pragma unroll
            for (int r = 0; r < 16; r++) D1[I][r] *= rs1;
        }
      }
      {
        unsigned PDt[2][4][2];
#pragma unroll
        for (int I = 0; I < 2; I++)
#pragma unroll
          for (int j = 0; j < 4; j++) {
            PDt[I][j][0] = pk2t(D0[I][4 * j + 0], D0[I][4 * j + 1]);
            PDt[I][j][1] = pk2t(D0[I][4 * j + 2], D0[I][4 * j + 3]);
          }
#pragma unroll
        for (int kap = 0; kap < 4; kap++) {
          const int Ip = kap >> 1, e2 = 2 * (kap & 1);
          unsigned x0 = PDt[Ip][e2][0], y0 = PDt[Ip][e2 + 1][0];
          unsigned x1 = PDt[Ip][e2][1], y1 = PDt[Ip][e2 + 1][1];
          pswap(x0, y0);
          pswap(x1, y1);
          Bf0[kap][J][0] = x0;
          Bf0[kap][J][1] = x1;
          Bf0[kap][J][2] = y0;
          Bf0[kap][J][3] = y1;
        }
      }
      if (do1) {
        unsigned PDt[2][4][2];
#pragma unroll
        for (int I = 0; I < 2; I++)
#pragma unroll
          for (int j = 0; j < 4; j++) {
            PDt[I][j][0] = pk2t(D1[I][4 * j + 0], D1[I][4 * j + 1]);
            PDt[I][j][1] = pk2t(D1[I][4 * j + 2], D1[I][4 * j + 3]);
          }
#pragma unroll
        for (int kap = 0; kap < 4; kap++) {
          const int Ip = kap >> 1, e2 = 2 * (kap & 1);
          unsigned x0 = PDt[Ip][e2][0], y0 = PDt[Ip][e2 + 1][0];
          unsigned x1 = PDt[Ip][e2][1], y1 = PDt[Ip][e2 + 1][1];
          pswap(x0, y0);
          pswap(x1, y1);
          Bf1[kap][J][0] = x0;
          Bf1[kap][J][1] = x1;
          Bf1[kap][J][2] = y0;
          Bf1[kap][J][3] = y1;
        }
      }
    }
  }
  // Coalesced fragment-major stores for both jobs (B-frags == A-frags of X^T)
  {
    uint4* Xj0 = XT + (size_t)job0 * 512 + L;
    uint4* Xj1 = XT + (size_t)job1 * 512 + L;
#pragma unroll
    for (int J = 0; J < 2; J++)
#pragma unroll
      for (int kap = 0; kap < 4; kap++) {
        Xj0[(J * 4 + kap) * 64] =
            make_uint4(Bf0[kap][J][0], Bf0[kap][J][1], Bf0[kap][J][2], Bf0[kap][J][3]);
        Xj1[(J * 4 + kap) * 64] =
            make_uint4(Bf1[kap][J][0], Bf1[kap][J][1], Bf1[kap][J][2], Bf1[kap][J][3]);
      }
  }
  if (L == 0) {
    rlog[job0] = logacc0;
    rlog[job1] = logacc1;
  }
}

// ---------- K2: TREE TAIL, transposed algebra (r2-verified, unchanged). ----------
__global__ __launch_bounds__(256) void k_tail(const uint4* __restrict__ XT,
                                              const float* __restrict__ rlog,
                                              const float* __restrict__ score,
                                              const int* __restrict__ x,
                                              const float* __restrict__ embed,
                                              const float* __restrict__ W,
                                              const float* __restrict__ bias,
                                              const float* __restrict__ trans,
                                              const int* __restrict__ tags,
                                              float* __restrict__ out) {
  __shared__ __align__(16) unsigned short Ptile[4][4096];  // 64x64 per wave (32 KB)
  __shared__ __align__(16) float vS[64];
  __shared__ float tlg[4];
  const int wv = threadIdx.x >> 6, L = threadIdx.x & 63;
  const int b = blockIdx.x;
  const int nh = L & 31, hh = L >> 5;
  const int* tg = tags + (size_t)b * L_;
  const f32x16 Z = {};
  unsigned Bf[4][2][4];

  const uint4* Sb4 = XT + ((size_t)(b * C_ + 8 * wv)) * 512 + L;
  {
    float plog = 0.f;
#pragma unroll
    for (int kap = 0; kap < 4; kap++)
#pragma unroll
      for (int J = 0; J < 2; J++)
#pragma unroll
        for (int dw = 0; dw < 4; dw++) {
          int k0 = 16 * kap + 8 * hh + 2 * dw, n = 32 * J + nh;
          unsigned u = 0;
          if (k0 == n) u = 0x3F80u;
          if (k0 + 1 == n) u = 0x3F800000u;
          Bf[kap][J][dw] = u;
        }
    uint4 Aq[2][4], Aqn[2][4];
#pragma unroll
    for (int I = 0; I < 2; I++)
#pragma unroll
      for (int kap = 0; kap < 4; kap++)
        Aq[I][kap] = Sb4[7 * 512 + (I * 4 + kap) * 64];
    for (int rr = 0; rr < 8; rr++) {
      const int r = 7 - rr;
      if (r > 0) {
#pragma unroll
        for (int I = 0; I < 2; I++)
#pragma unroll
          for (int kap = 0; kap < 4; kap++)
            Aqn[I][kap] = Sb4[(size_t)(r - 1) * 512 + (I * 4 + kap) * 64];
      }
      short8 Ap[2][4];
#pragma unroll
      for (int I = 0; I < 2; I++)
#pragma unroll
        for (int kap = 0; kap < 4; kap++)
          Ap[I][kap] = __builtin_bit_cast(short8, Aq[I][kap]);
      const bool last = (r == 0);
      float rsw = 1.0f;
#pragma unroll
      for (int J = 0; J < 2; J++) {
        f32x16 D[2];
#pragma unroll
        for (int I = 0; I < 2; I++) {
          short8 b0 = __builtin_bit_cast(short8,
              make_uint4(Bf[0][J][0], Bf[0][J][1], Bf[0][J][2], Bf[0][J][3]));
          f32x16 d = __builtin_amdgcn_mfma_f32_32x32x16_bf16(Ap[I][0], b0, Z, 0, 0, 0);
#pragma unroll
          for (int kap = 1; kap < 4; kap++) {
            short8 bk = __builtin_bit_cast(short8,
                make_uint4(Bf[kap][J][0], Bf[kap][J][1], Bf[kap][J][2], Bf[kap][J][3]));
            d = __builtin_amdgcn_mfma_f32_32x32x16_bf16(Ap[I][kap], bk, d, 0, 0, 0);
          }
          D[I] = d;
        }
        if (J == 0) {
          float mx = D[0][0];
#pragma unroll
          for (int I = 0; I < 2; I++)
#pragma unroll
            for (int rr2 = 0; rr2 < 16; rr2++) mx = fmaxf(mx, D[I][rr2]);
#pragma unroll
          for (int off = 1; off < 64; off <<= 1) mx = fmaxf(mx, __shfl_xor(mx, off));
          mx = fmaxf(mx, 1e-30f);
          rsw = 1.0f / mx;
          plog += __logf(mx);
        }
#pragma unroll
        for (int I = 0; I < 2; I++)
#pragma unroll
          for (int rr2 = 0; rr2 < 16; rr2++) D[I][rr2] *= rsw;
        unsigned PDt[2][4][2];
#pragma unroll
        for (int I = 0; I < 2; I++)
#pragma unroll
          for (int j = 0; j < 4; j++) {
            PDt[I][j][0] = pk2t(D[I][4 * j + 0], D[I][4 * j + 1]);
            PDt[I][j][1] = pk2t(D[I][4 * j + 2], D[I][4 * j + 3]);
          }
        if (last) {
          unsigned short* Xrow = Ptile[wv] + 32 * J + nh;
#pragma unroll
          for (int I = 0; I < 2; I++)
#pragma unroll
            for (int j = 0; j < 4; j++)
#pragma unroll
              for (int pp = 0; pp < 2; pp++) {
                const int rw = 32 * I + 8 * j + 4 * hh + 2 * pp;
                Xrow[rw * 64] = (unsigned short)(PDt[I][j][pp] & 0xffffu);
                Xrow[(rw + 1) * 64] = (unsigned short)(PDt[I][j][pp] >> 16);
              }
        } else {
#pragma unroll
          for (int kap = 0; kap < 4; kap++) {
            const int Ip = kap >> 1, e2 = 2 * (kap & 1);
            unsigned x0 = PDt[Ip][e2][0], y0 = PDt[Ip][e2 + 1][0];
            unsigned x1 = PDt[Ip][e2][1], y1 = PDt[Ip][e2 + 1][1];
            pswap(x0, y0);
            pswap(x1, y1);
            Bf[kap][J][0] = x0;
            Bf[kap][J][1] = x1;
            Bf[kap][J][2] = y0;
            Bf[kap][J][3] = y1;
          }
        }
      }
      if (r > 0) {
#pragma unroll
        for (int I = 0; I < 2; I++)
#pragma unroll
          for (int kap = 0; kap < 4; kap++)
            Aq[I][kap] = Aqn[I][kap];
      }
    }
    if (L == 0) tlg[wv] = plog;
  }
  __syncthreads();
  if (threadIdx.x >= 64) return;  // wave 0 finishes alone

  float tlog = (tlg[0] + tlg[1]) + (tlg[2] + tlg[3]);

  const int i = L;
  const float* er0 = embed + (size_t)x[(size_t)b * L_] * 256;
  float e0 = bias[i], e1 = 0.f, e2 = 0.f, e3 = 0.f;
#pragma unroll 16
  for (int d = 0; d < 256; d += 4) {
    e0 = fmaf(er0[d + 0], W[(d + 0) * T_ + i], e0);
    e1 = fmaf(er0[d + 1], W[(d + 1) * T_ + i], e1);
    e2 = fmaf(er0[d + 2], W[(d + 2) * T_ + i], e2);
    e3 = fmaf(er0[d + 3], W[(d + 3) * T_ + i], e3);
  }
  float e = (e0 + e1) + (e2 + e3);
  float mr = e;
#pragma unroll
  for (int off = 1; off < 64; off <<= 1) mr = fmaxf(mr, __shfl_xor(mr, off));
  float pex = __expf(e - mr);
  float sr = pex;
#pragma unroll
  for (int off = 1; off < 64; off <<= 1) sr += __shfl_xor(sr, off);
  const int t0 = tg[0];
  float sc = score[b];
  sc += (__shfl(e, t0) - mr) - __logf(sr);
  sc += trans[t0] + trans[tg[L_ - 1] * T_ + 1];
  vS[i] = __expf(trans[i]) * (pex / sr);
  float rl = (i < 32) ? rlog[b * C_ + i] : 0.f;
#pragma unroll
  for (int off = 1; off < 64; off <<= 1) rl += __shfl_xor(rl, off);

  float tacc = 0.f;
  {
#pragma unroll
    for (int kap = 0; kap < 4; kap++)
#pragma unroll
      for (int J = 0; J < 2; J++)
#pragma unroll
        for (int dw = 0; dw < 4; dw++) {
          int k0 = 16 * kap + 8 * hh + 2 * dw, n = 32 * J + nh;
          unsigned u = 0;
          if (k0 == n) u = 0x3F80u;
          if (k0 + 1 == n) u = 0x3F800000u;
          Bf[kap][J][dw] = u;
        }
    for (int rr = 0; rr < 4; rr++) {
      const int r = 3 - rr;
      short8 Ap[2][4];
#pragma unroll
      for (int I = 0; I < 2; I++)
#pragma unroll
        for (int kap = 0; kap < 4; kap++)
          Ap[I][kap] = *(const short8*)&Ptile[r][(32 * I + nh) * 64 + 16 * kap + 8 * hh];
      const bool last = (r == 0);
      float rsw = 1.0f;
#pragma unroll
      for (int J = 0; J < 2; J++) {
        f32x16 D[2];
#pragma unroll
        for (int I = 0; I < 2; I++) {
          short8 b0 = __builtin_bit_cast(short8,
              make_uint4(Bf[0][J][0], Bf[0][J][1], Bf[0][J][2], Bf[0][J][3]));
          f32x16 d = __builtin_amdgcn_mfma_f32_32x32x16_bf16(Ap[I][0], b0, Z, 0, 0, 0);
#pragma unroll
          for (int kap = 1; kap < 4; kap++) {
            short8 bk = __builtin_bit_cast(short8,
                make_uint4(Bf[kap][J][0], Bf[kap][J][1], Bf[kap][J][2], Bf[kap][J][3]));
            d = __builtin_amdgcn_mfma_f32_32x32x16_bf16(Ap[I][kap], bk, d, 0, 0, 0);
          }
          D[I] = d;
        }
        if (J == 0) {
          float mx = D[0][0];
#pragma unroll
          for (int I = 0; I < 2; I++)
#pragma unroll
            for (int rr2 = 0; rr2 < 16; rr2++) mx = fmaxf(mx, D[I][rr2]);
#pragma unroll
          for (int off = 1; off < 64; off <<= 1) mx = fmaxf(mx, __shfl_xor(mx, off));
          mx = fmaxf(mx, 1e-30f);
          rsw = 1.0f / mx;
          tlog += __logf(mx);
        }
#pragma unroll
        for (int I = 0; I < 2; I++)
#pragma unroll
          for (int rr2 = 0; rr2 < 16; rr2++) D[I][rr2] *= rsw;
        if (last) {
          float dJ = 0.f;
#pragma unroll
          for (int I = 0; I < 2; I++)
#pragma unroll
            for (int r2 = 0; r2 < 16; r2++)
              dJ = fmaf(D[I][r2], vS[32 * I + (r2 & 3) + 8 * (r2 >> 2) + 4 * hh], dJ);
          tacc = fmaf(__expf(trans[(32 * J + nh) * T_ + 1]), dJ, tacc);
        } else {
          unsigned PDt[2][4][2];
#pragma unroll
          for (int I = 0; I < 2; I++)
#pragma unroll
            for (int j = 0; j < 4; j++) {
              PDt[I][j][0] = pk2t(D[I][4 * j + 0], D[I][4 * j + 1]);
              PDt[I][j][1] = pk2t(D[I][4 * j + 2], D[I][4 * j + 3]);
            }
#pragma unroll
          for (int kap = 0; kap < 4; kap++) {
            const int Ip = kap >> 1, e2b = 2 * (kap & 1);
            unsigned x0 = PDt[Ip][e2b][0], y0 = PDt[Ip][e2b + 1][0];
            unsigned x1 = PDt[Ip][e2b][1], y1 = PDt[Ip][e2b + 1][1];
            pswap(x0, y0);
            pswap(x1, y1);
            Bf[kap][J][0] = x0;
            Bf[kap][J][1] = x1;
            Bf[kap][J][2] = y0;
            Bf[kap][J][3] = y1;
          }
        }
      }
    }
  }
  float t2 = tacc;
#pragma unroll
  for (int off = 1; off < 64; off <<= 1) t2 += __shfl_xor(t2, off);
  if (i == 0) {
    const float logz = rl + tlog + __logf(t2);
    atomicAdd(out, -(sc - logz));
  }
}

extern "C" void kernel_launch(void* const* d_in, const int* in_sizes, int n_in,
                              void* d_out, int out_size, void* d_ws, size_t ws_size,
                              hipStream_t stream) {
  const int* x = (const int*)d_in[0];
  const int* tags = (const int*)d_in[1];
  const float* embed = (const float*)d_in[3];
  const float* W = (const float*)d_in[4];
  const float* bias = (const float*)d_in[5];
  const float* trans = (const float*)d_in[6];

  char* ws = (char*)d_ws;
  uint4* XT = (uint4*)ws;                                            // 32 MB
  float* rlog = (float*)(ws + (size_t)C_ * 1048576);                 // 16 KB
  float* score = (float*)((char*)rlog + 4096 * 4);                   // 512 B
  unsigned short* Wswz = (unsigned short*)((char*)score + 128 * 4);  // 32 KB
  float* out = (float*)d_out;

  k_prep<<<16, 256, 0, stream>>>(W, Wswz, score, out);
  k_scan<<<B_ * C_ / 8, 256, 0, stream>>>(x, tags, embed, Wswz, bias, trans, XT, rlog, score);
  k_tail<<<B_, 256, 0, stream>>>(XT, rlog, score, x, embed, W, bias, trans, tags, out);
}

// Round 8
// 188.461 us; speedup vs baseline: 1.2626x; 1.2626x over previous
//
#include <hip/hip_runtime.h>
#include <hip/hip_bf16.h>

#define B_ 128
#define L_ 1024
#define T_ 64
#define CSH 5
#define C_ 32

using short8 = __attribute__((ext_vector_type(8))) short;
using f32x4  = __attribute__((ext_vector_type(4))) float;
using f32x16 = __attribute__((ext_vector_type(16))) float;

static __device__ __forceinline__ unsigned short bfb(float x) {
  return __builtin_bit_cast(unsigned short, __float2bfloat16(x));
}
static __device__ __forceinline__ float asf(unsigned u) { return __builtin_bit_cast(float, u); }
static __device__ __forceinline__ unsigned pk2(float lo, float hi) {
  __hip_bfloat162 h = __float22bfloat162_rn(float2{lo, hi});
  unsigned u;
  __builtin_memcpy(&u, &h, 4);
  return u;
}
// packed 2xf32 -> bf16x2 dword by TRUNCATION: one v_perm_b32 (verified r8)
static __device__ __forceinline__ unsigned pk2t(float lo, float hi) {
  return __builtin_amdgcn_perm(__builtin_bit_cast(unsigned, hi),
                               __builtin_bit_cast(unsigned, lo), 0x07060302u);
}
// gfx950 half-wave exchange (verified r5)
static __device__ __forceinline__ void pswap(unsigned& x, unsigned& y) {
  asm("v_permlane32_swap_b32 %0, %1" : "+v"(x), "+v"(y));
}

// ---------- K0: build Wswz table + zero score/out (r2-verified, 16 blocks) ----------
__global__ __launch_bounds__(256) void k_prep(const float* __restrict__ W,
                                              unsigned short* __restrict__ Wswz,
                                              float* __restrict__ score,
                                              float* __restrict__ out) {
  if (blockIdx.x == 0) {
    if (threadIdx.x < 128) score[threadIdx.x] = 0.f;
    if (threadIdx.x == 0) out[0] = 0.f;
  }
  const int t = blockIdx.x * 256 + threadIdx.x;
  const int e = t * 4, k = e >> 6, n0 = e & 63;
  float4 w4 = *(const float4*)(W + e);
  const int base = ((k >> 5) << 11) + ((n0 >> 4) << 9) + (((k >> 3) & 3) << 7) +
                   ((n0 & 15) << 3) + (k & 7);
  Wswz[base + 0]  = bfb(w4.x);
  Wswz[base + 8]  = bfb(w4.y);
  Wswz[base + 16] = bfb(w4.z);
  Wswz[base + 24] = bfb(w4.w);
}

// ---------- K1: emission + scan + gold (r2-verified structure: 4 waves/block, one
// job per wave). VALU diet (issue-bound per r2..r6 counter analysis):
//   (1) Ftile stored as f32 (32KB/block) -> no per-step bf16 unpack (−32 ops/step),
//       no emission-side bfb converts; F multiply numerics move closer to f32 ref.
//   (2) F assembled into f32x16 Fv and applied as whole-vector multiplies ->
//       v_pk_mul_f32 (2 f32/instr): 64 mults issue as 32.
__global__ __launch_bounds__(256) void k_scan(const int* __restrict__ x,
                                              const int* __restrict__ tags,
                                              const float* __restrict__ embed,
                                              const unsigned short* __restrict__ Wswz,
                                              const float* __restrict__ bias,
                                              const float* __restrict__ trans,
                                              uint4* __restrict__ XT,
                                              float* __restrict__ rlog,
                                              float* __restrict__ score) {
  __shared__ __align__(16) float Ftile[4][2048];  // 32 KB: 4 jobs x 32 rows x 64 f32
  const int wv = threadIdx.x >> 6, L = threadIdx.x & 63;
  const int job = blockIdx.x * 4 + wv;
  const int c = job & (C_ - 1);
  const int b = job >> CSH;
  const int K = (1023 + C_ - 1) >> CSH;
  const int a = 1 + c * K;
  const int len = min(K, 1024 - a);
  const int nh = L & 31, hh = L >> 5;
  const int m = L & 15, q = L >> 4;
  float* Ft = Ftile[wv];
  const int* tg = tags + (size_t)b * L_;

  const float bj0 = bias[m], bj1 = bias[16 + m], bj2 = bias[32 + m], bj3 = bias[48 + m];
  for (int p = 0; p < 2; p++) {
    int tok = a + 16 * p + m;
    if (tok > 1023) tok = 1023;
    const float* er = embed + (size_t)x[b * 1024 + tok] * 256;
    f32x4 acc[4] = {{0.f,0.f,0.f,0.f},{0.f,0.f,0.f,0.f},{0.f,0.f,0.f,0.f},{0.f,0.f,0.f,0.f}};
#pragma unroll
    for (int kap = 0; kap < 8; kap++) {
      float4 p0 = *(const float4*)(er + 32 * kap + 8 * q);
      float4 p1 = *(const float4*)(er + 32 * kap + 8 * q + 4);
      unsigned u0 = pk2(p0.x, p0.y), u1 = pk2(p0.z, p0.w);
      unsigned u2 = pk2(p1.x, p1.y), u3 = pk2(p1.z, p1.w);
      short8 af = __builtin_bit_cast(short8, make_uint4(u0, u1, u2, u3));
#pragma unroll
      for (int u = 0; u < 4; u++) {
        short8 bf8 = *(const short8*)&Wswz[kap * 2048 + u * 512 + q * 128 + m * 8];
        acc[u] = __builtin_amdgcn_mfma_f32_16x16x32_bf16(af, bf8, acc[u], 0, 0, 0);
      }
    }
#pragma unroll
    for (int r = 0; r < 4; r++) {
      float e0 = acc[0][r] + bj0, e1 = acc[1][r] + bj1;
      float e2 = acc[2][r] + bj2, e3 = acc[3][r] + bj3;
      float mr = fmaxf(fmaxf(e0, e1), fmaxf(e2, e3));
#pragma unroll
      for (int off = 1; off < 16; off <<= 1) mr = fmaxf(mr, __shfl_xor(mr, off));
      float x0 = __expf(e0 - mr), x1 = __expf(e1 - mr);
      float x2 = __expf(e2 - mr), x3 = __expf(e3 - mr);
      float sr = (x0 + x1) + (x2 + x3);
#pragma unroll
      for (int off = 1; off < 16; off <<= 1) sr += __shfl_xor(sr, off);
      float rs = 1.0f / sr;
      const int row = 16 * p + 4 * q + r;
      Ft[row * 64 + m]      = x0 * rs;
      Ft[row * 64 + 16 + m] = x1 * rs;
      Ft[row * 64 + 32 + m] = x2 * rs;
      Ft[row * 64 + 48 + m] = x3 * rs;
    }
  }
  // distributed gold partials (r14-verified; now direct f32 log)
  {
    float gold = 0.f;
    if (L < len) {
      const int tga = tg[a + L], tgp = tg[a - 1 + L];
      gold = __logf(Ft[L * 64 + tga]) + trans[tgp * T_ + tga];
    }
#pragma unroll
    for (int off = 1; off < 64; off <<= 1) gold += __shfl_xor(gold, off);
    if (L == 0) atomicAdd(&score[b], gold);
  }

  short8 Af[2][4];
#pragma unroll
  for (int I = 0; I < 2; I++)
#pragma unroll
    for (int kap = 0; kap < 4; kap++) {
      short8 aa;
#pragma unroll
      for (int d = 0; d < 8; d++) {
        const int k = 16 * kap + 8 * hh + d;
        aa[d] = (short)bfb(__expf(trans[k * T_ + 32 * I + nh]));
      }
      Af[I][kap] = aa;
    }
  unsigned Bf[4][2][4];
#pragma unroll
  for (int kap = 0; kap < 4; kap++)
#pragma unroll
    for (int J = 0; J < 2; J++)
#pragma unroll
      for (int dw = 0; dw < 4; dw++) {
        int k0 = 16 * kap + 8 * hh + 2 * dw, n = 32 * J + nh;
        unsigned u = 0;
        if (k0 == n) u = 0x3F80u;
        if (k0 + 1 == n) u = 0x3F800000u;
        Bf[kap][J][dw] = u;
      }

  float logacc = 0.f;
  const f32x16 Z = {};
  for (int s = 0; s < len; s++) {  // --- r13-verified scan loop, f32-F + pk-mul ---
    f32x16 Fv[2];
#pragma unroll
    for (int I = 0; I < 2; I++)
#pragma unroll
      for (int j = 0; j < 4; j++) {
        f32x4 f4 = *(const f32x4*)&Ft[s * 64 + 32 * I + 8 * j + 4 * hh];
#pragma unroll
        for (int e = 0; e < 4; e++) Fv[I][4 * j + e] = f4[e];
      }
    const bool rn = ((s & 15) == 15);
    float rs = 1.0f;
#pragma unroll
    for (int J = 0; J < 2; J++) {
      f32x16 D[2];
#pragma unroll
      for (int I = 0; I < 2; I++) {
        short8 b0 = __builtin_bit_cast(short8,
            make_uint4(Bf[0][J][0], Bf[0][J][1], Bf[0][J][2], Bf[0][J][3]));
        f32x16 d = __builtin_amdgcn_mfma_f32_32x32x16_bf16(Af[I][0], b0, Z, 0, 0, 0);
#pragma unroll
        for (int kap = 1; kap < 4; kap++) {
          short8 bk = __builtin_bit_cast(short8,
              make_uint4(Bf[kap][J][0], Bf[kap][J][1], Bf[kap][J][2], Bf[kap][J][3]));
          d = __builtin_amdgcn_mfma_f32_32x32x16_bf16(Af[I][kap], bk, d, 0, 0, 0);
        }
        D[I] = d;
      }
      // diagonal F multiply as whole-vector ops -> v_pk_mul_f32
      D[0] *= Fv[0];
      D[1] *= Fv[1];
      if (rn) {
        if (J == 0) {
          float mx = D[0][0];
#pragma unroll
          for (int I = 0; I < 2; I++)
#pragma unroll
            for (int r = 0; r < 16; r++) mx = fmaxf(mx, D[I][r]);
#pragma unroll
          for (int off = 1; off < 64; off <<= 1) mx = fmaxf(mx, __shfl_xor(mx, off));
          rs = 1.0f / mx;
          logacc += __logf(mx);
        }
        D[0] *= rs;
        D[1] *= rs;
      }
      unsigned PDt[2][4][2];
#pragma unroll
      for (int I = 0; I < 2; I++)
#pragma unroll
        for (int j = 0; j < 4; j++) {
          PDt[I][j][0] = pk2t(D[I][4 * j + 0], D[I][4 * j + 1]);
          PDt[I][j][1] = pk2t(D[I][4 * j + 2], D[I][4 * j + 3]);
        }
#pragma unroll
      for (int kap = 0; kap < 4; kap++) {
        const int Ip = kap >> 1, e2 = 2 * (kap & 1);
        unsigned x0 = PDt[Ip][e2][0], y0 = PDt[Ip][e2 + 1][0];
        unsigned x1 = PDt[Ip][e2][1], y1 = PDt[Ip][e2 + 1][1];
        pswap(x0, y0);
        pswap(x1, y1);
        Bf[kap][J][0] = x0;
        Bf[kap][J][1] = x1;
        Bf[kap][J][2] = y0;
        Bf[kap][J][3] = y1;
      }
    }
  }
  // Coalesced fragment-major store: per (J,kap), 64 lanes write 1KB contiguous.
  // Bytes are B-frags of X_c == A-frags of X_c^T (MFMA A/B lane symmetry).
  {
    uint4* Xj = XT + (size_t)job * 512 + L;
#pragma unroll
    for (int J = 0; J < 2; J++)
#pragma unroll
      for (int kap = 0; kap < 4; kap++)
        Xj[(J * 4 + kap) * 64] =
            make_uint4(Bf[kap][J][0], Bf[kap][J][1], Bf[kap][J][2], Bf[kap][J][3]);
  }
  if (L == 0) rlog[job] = logacc;
}

// ---------- K2: TREE TAIL, transposed algebra (r2-verified, unchanged). ----------
__global__ __launch_bounds__(256) void k_tail(const uint4* __restrict__ XT,
                                              const float* __restrict__ rlog,
                                              const float* __restrict__ score,
                                              const int* __restrict__ x,
                                              const float* __restrict__ embed,
                                              const float* __restrict__ W,
                                              const float* __restrict__ bias,
                                              const float* __restrict__ trans,
                                              const int* __restrict__ tags,
                                              float* __restrict__ out) {
  __shared__ __align__(16) unsigned short Ptile[4][4096];  // 64x64 per wave (32 KB)
  __shared__ __align__(16) float vS[64];
  __shared__ float tlg[4];
  const int wv = threadIdx.x >> 6, L = threadIdx.x & 63;
  const int b = blockIdx.x;
  const int nh = L & 31, hh = L >> 5;
  const int* tg = tags + (size_t)b * L_;
  const f32x16 Z = {};
  unsigned Bf[4][2][4];

  const uint4* Sb4 = XT + ((size_t)(b * C_ + 8 * wv)) * 512 + L;
  {
    float plog = 0.f;
#pragma unroll
    for (int kap = 0; kap < 4; kap++)
#pragma unroll
      for (int J = 0; J < 2; J++)
#pragma unroll
        for (int dw = 0; dw < 4; dw++) {
          int k0 = 16 * kap + 8 * hh + 2 * dw, n = 32 * J + nh;
          unsigned u = 0;
          if (k0 == n) u = 0x3F80u;
          if (k0 + 1 == n) u = 0x3F800000u;
          Bf[kap][J][dw] = u;
        }
    uint4 Aq[2][4], Aqn[2][4];
#pragma unroll
    for (int I = 0; I < 2; I++)
#pragma unroll
      for (int kap = 0; kap < 4; kap++)
        Aq[I][kap] = Sb4[7 * 512 + (I * 4 + kap) * 64];
    for (int rr = 0; rr < 8; rr++) {
      const int r = 7 - rr;
      if (r > 0) {
#pragma unroll
        for (int I = 0; I < 2; I++)
#pragma unroll
          for (int kap = 0; kap < 4; kap++)
            Aqn[I][kap] = Sb4[(size_t)(r - 1) * 512 + (I * 4 + kap) * 64];
      }
      short8 Ap[2][4];
#pragma unroll
      for (int I = 0; I < 2; I++)
#pragma unroll
        for (int kap = 0; kap < 4; kap++)
          Ap[I][kap] = __builtin_bit_cast(short8, Aq[I][kap]);
      const bool last = (r == 0);
      float rsw = 1.0f;
#pragma unroll
      for (int J = 0; J < 2; J++) {
        f32x16 D[2];
#pragma unroll
        for (int I = 0; I < 2; I++) {
          short8 b0 = __builtin_bit_cast(short8,
              make_uint4(Bf[0][J][0], Bf[0][J][1], Bf[0][J][2], Bf[0][J][3]));
          f32x16 d = __builtin_amdgcn_mfma_f32_32x32x16_bf16(Ap[I][0], b0, Z, 0, 0, 0);
#pragma unroll
          for (int kap = 1; kap < 4; kap++) {
            short8 bk = __builtin_bit_cast(short8,
                make_uint4(Bf[kap][J][0], Bf[kap][J][1], Bf[kap][J][2], Bf[kap][J][3]));
            d = __builtin_amdgcn_mfma_f32_32x32x16_bf16(Ap[I][kap], bk, d, 0, 0, 0);
          }
          D[I] = d;
        }
        if (J == 0) {
          float mx = D[0][0];
#pragma unroll
          for (int I = 0; I < 2; I++)
#pragma unroll
            for (int rr2 = 0; rr2 < 16; rr2++) mx = fmaxf(mx, D[I][rr2]);
#pragma unroll
          for (int off = 1; off < 64; off <<= 1) mx = fmaxf(mx, __shfl_xor(mx, off));
          mx = fmaxf(mx, 1e-30f);
          rsw = 1.0f / mx;
          plog += __logf(mx);
        }
#pragma unroll
        for (int I = 0; I < 2; I++)
#pragma unroll
          for (int rr2 = 0; rr2 < 16; rr2++) D[I][rr2] *= rsw;
        unsigned PDt[2][4][2];
#pragma unroll
        for (int I = 0; I < 2; I++)
#pragma unroll
          for (int j = 0; j < 4; j++) {
            PDt[I][j][0] = pk2t(D[I][4 * j + 0], D[I][4 * j + 1]);
            PDt[I][j][1] = pk2t(D[I][4 * j + 2], D[I][4 * j + 3]);
          }
        if (last) {
          unsigned short* Xrow = Ptile[wv] + 32 * J + nh;
#pragma unroll
          for (int I = 0; I < 2; I++)
#pragma unroll
            for (int j = 0; j < 4; j++)
#pragma unroll
              for (int pp = 0; pp < 2; pp++) {
                const int rw = 32 * I + 8 * j + 4 * hh + 2 * pp;
                Xrow[rw * 64] = (unsigned short)(PDt[I][j][pp] & 0xffffu);
                Xrow[(rw + 1) * 64] = (unsigned short)(PDt[I][j][pp] >> 16);
              }
        } else {
#pragma unroll
          for (int kap = 0; kap < 4; kap++) {
            const int Ip = kap >> 1, e2 = 2 * (kap & 1);
            unsigned x0 = PDt[Ip][e2][0], y0 = PDt[Ip][e2 + 1][0];
            unsigned x1 = PDt[Ip][e2][1], y1 = PDt[Ip][e2 + 1][1];
            pswap(x0, y0);
            pswap(x1, y1);
            Bf[kap][J][0] = x0;
            Bf[kap][J][1] = x1;
            Bf[kap][J][2] = y0;
            Bf[kap][J][3] = y1;
          }
        }
      }
      if (r > 0) {
#pragma unroll
        for (int I = 0; I < 2; I++)
#pragma unroll
          for (int kap = 0; kap < 4; kap++)
            Aq[I][kap] = Aqn[I][kap];
      }
    }
    if (L == 0) tlg[wv] = plog;
  }
  __syncthreads();
  if (threadIdx.x >= 64) return;  // wave 0 finishes alone

  float tlog = (tlg[0] + tlg[1]) + (tlg[2] + tlg[3]);

  const int i = L;
  const float* er0 = embed + (size_t)x[(size_t)b * L_] * 256;
  float e0 = bias[i], e1 = 0.f, e2 = 0.f, e3 = 0.f;
#pragma unroll 16
  for (int d = 0; d < 256; d += 4) {
    e0 = fmaf(er0[d + 0], W[(d + 0) * T_ + i], e0);
    e1 = fmaf(er0[d + 1], W[(d + 1) * T_ + i], e1);
    e2 = fmaf(er0[d + 2], W[(d + 2) * T_ + i], e2);
    e3 = fmaf(er0[d + 3], W[(d + 3) * T_ + i], e3);
  }
  float e = (e0 + e1) + (e2 + e3);
  float mr = e;
#pragma unroll
  for (int off = 1; off < 64; off <<= 1) mr = fmaxf(mr, __shfl_xor(mr, off));
  float pex = __expf(e - mr);
  float sr = pex;
#pragma unroll
  for (int off = 1; off < 64; off <<= 1) sr += __shfl_xor(sr, off);
  const int t0 = tg[0];
  float sc = score[b];
  sc += (__shfl(e, t0) - mr) - __logf(sr);
  sc += trans[t0] + trans[tg[L_ - 1] * T_ + 1];
  vS[i] = __expf(trans[i]) * (pex / sr);
  float rl = (i < 32) ? rlog[b * C_ + i] : 0.f;
#pragma unroll
  for (int off = 1; off < 64; off <<= 1) rl += __shfl_xor(rl, off);

  float tacc = 0.f;
  {
#pragma unroll
    for (int kap = 0; kap < 4; kap++)
#pragma unroll
      for (int J = 0; J < 2; J++)
#pragma unroll
        for (int dw = 0; dw < 4; dw++) {
          int k0 = 16 * kap + 8 * hh + 2 * dw, n = 32 * J + nh;
          unsigned u = 0;
          if (k0 == n) u = 0x3F80u;
          if (k0 + 1 == n) u = 0x3F800000u;
          Bf[kap][J][dw] = u;
        }
    for (int rr = 0; rr < 4; rr++) {
      const int r = 3 - rr;
      short8 Ap[2][4];
#pragma unroll
      for (int I = 0; I < 2; I++)
#pragma unroll
        for (int kap = 0; kap < 4; kap++)
          Ap[I][kap] = *(const short8*)&Ptile[r][(32 * I + nh) * 64 + 16 * kap + 8 * hh];
      const bool last = (r == 0);
      float rsw = 1.0f;
#pragma unroll
      for (int J = 0; J < 2; J++) {
        f32x16 D[2];
#pragma unroll
        for (int I = 0; I < 2; I++) {
          short8 b0 = __builtin_bit_cast(short8,
              make_uint4(Bf[0][J][0], Bf[0][J][1], Bf[0][J][2], Bf[0][J][3]));
          f32x16 d = __builtin_amdgcn_mfma_f32_32x32x16_bf16(Ap[I][0], b0, Z, 0, 0, 0);
#pragma unroll
          for (int kap = 1; kap < 4; kap++) {
            short8 bk = __builtin_bit_cast(short8,
                make_uint4(Bf[kap][J][0], Bf[kap][J][1], Bf[kap][J][2], Bf[kap][J][3]));
            d = __builtin_amdgcn_mfma_f32_32x32x16_bf16(Ap[I][kap], bk, d, 0, 0, 0);
          }
          D[I] = d;
        }
        if (J == 0) {
          float mx = D[0][0];
#pragma unroll
          for (int I = 0; I < 2; I++)
#pragma unroll
            for (int rr2 = 0; rr2 < 16; rr2++) mx = fmaxf(mx, D[I][rr2]);
#pragma unroll
          for (int off = 1; off < 64; off <<= 1) mx = fmaxf(mx, __shfl_xor(mx, off));
          mx = fmaxf(mx, 1e-30f);
          rsw = 1.0f / mx;
          tlog += __logf(mx);
        }
#pragma unroll
        for (int I = 0; I < 2; I++)
#pragma unroll
          for (int rr2 = 0; rr2 < 16; rr2++) D[I][rr2] *= rsw;
        if (last) {
          float dJ = 0.f;
#pragma unroll
          for (int I = 0; I < 2; I++)
#pragma unroll
            for (int r2 = 0; r2 < 16; r2++)
              dJ = fmaf(D[I][r2], vS[32 * I + (r2 & 3) + 8 * (r2 >> 2) + 4 * hh], dJ);
          tacc = fmaf(__expf(trans[(32 * J + nh) * T_ + 1]), dJ, tacc);
        } else {
          unsigned PDt[2][4][2];
#pragma unroll
          for (int I = 0; I < 2; I++)
#pragma unroll
            for (int j = 0; j < 4; j++) {
              PDt[I][j][0] = pk2t(D[I][4 * j + 0], D[I][4 * j + 1]);
              PDt[I][j][1] = pk2t(D[I][4 * j + 2], D[I][4 * j + 3]);
            }
#pragma unroll
          for (int kap = 0; kap < 4; kap++) {
            const int Ip = kap >> 1, e2b = 2 * (kap & 1);
            unsigned x0 = PDt[Ip][e2b][0], y0 = PDt[Ip][e2b + 1][0];
            unsigned x1 = PDt[Ip][e2b][1], y1 = PDt[Ip][e2b + 1][1];
            pswap(x0, y0);
            pswap(x1, y1);
            Bf[kap][J][0] = x0;
            Bf[kap][J][1] = x1;
            Bf[kap][J][2] = y0;
            Bf[kap][J][3] = y1;
          }
        }
      }
    }
  }
  float t2 = tacc;
#pragma unroll
  for (int off = 1; off < 64; off <<= 1) t2 += __shfl_xor(t2, off);
  if (i == 0) {
    const float logz = rl + tlog + __logf(t2);
    atomicAdd(out, -(sc - logz));
  }
}

extern "C" void kernel_launch(void* const* d_in, const int* in_sizes, int n_in,
                              void* d_out, int out_size, void* d_ws, size_t ws_size,
                              hipStream_t stream) {
  const int* x = (const int*)d_in[0];
  const int* tags = (const int*)d_in[1];
  const float* embed = (const float*)d_in[3];
  const float* W = (const float*)d_in[4];
  const float* bias = (const float*)d_in[5];
  const float* trans = (const float*)d_in[6];

  char* ws = (char*)d_ws;
  uint4* XT = (uint4*)ws;                                            // 32 MB
  float* rlog = (float*)(ws + (size_t)C_ * 1048576);                 // 16 KB
  float* score = (float*)((char*)rlog + 4096 * 4);                   // 512 B
  unsigned short* Wswz = (unsigned short*)((char*)score + 128 * 4);  // 32 KB
  float* out = (float*)d_out;

  k_prep<<<16, 256, 0, stream>>>(W, Wswz, score, out);
  k_scan<<<32 * C_, 256, 0, stream>>>(x, tags, embed, Wswz, bias, trans, XT, rlog, score);
  k_tail<<<B_, 256, 0, stream>>>(XT, rlog, score, x, embed, W, bias, trans, tags, out);
}